// Round 8
// baseline (168.114 us; speedup 1.0000x reference)
//
#include <hip/hip_runtime.h>
#include <hip/hip_bf16.h>

#define BATCH 16384
#define FIN   768
#define FOUT  512

#define BK 32
#define NT (FIN / BK)   // 24 K-iterations
#define BMB 64          // batch rows per block -> 128 GEMM rows (stm+nstm)
#define BN 128          // feature cols per block (N-split x4)

typedef __attribute__((ext_vector_type(8))) short short8;
typedef __attribute__((ext_vector_type(4))) float floatx4;

// packed fp32x2 -> bf16x2, round-to-nearest-even (gfx940+ VOP3)
__device__ __forceinline__ unsigned int cvt_pk_bf16(float a, float b) {
    unsigned int r;
    asm("v_cvt_pk_bf16_f32 %0, %1, %2" : "=v"(r) : "v"(a), "v"(b));
    return r;
}

// async 16B global -> LDS DMA; HW scatters lane i to ldsbase + i*16
__device__ __forceinline__ void load_lds_16(const void* g, void* l) {
    __builtin_amdgcn_global_load_lds(
        (const __attribute__((address_space(1))) unsigned int*)g,
        (__attribute__((address_space(3))) unsigned int*)l,
        16, 0, 0);
}

// one-shot W1 fp32 -> bf16 (393216 elems, 8 per thread, 192 blocks)
__global__ __launch_bounds__(256) void cvt_w1(
    const float* __restrict__ W1, unsigned short* __restrict__ W1b)
{
    int base = (blockIdx.x * 256 + threadIdx.x) * 8;
    float4 a = *(const float4*)(W1 + base);
    float4 b = *(const float4*)(W1 + base + 4);
    uint4 o;
    o.x = cvt_pk_bf16(a.x, a.y); o.y = cvt_pk_bf16(a.z, a.w);
    o.z = cvt_pk_bf16(b.x, b.y); o.w = cvt_pk_bf16(b.z, b.w);
    *(uint4*)(W1b + base) = o;
}

// m97-shape: 1024 blocks x 256 threads (4 waves), 32 KB LDS/block ->
// EXACTLY 4 co-resident blocks per CU (16 waves/CU = the 128-combined-reg
// cap), all 1024 blocks resident simultaneously (no tail). Four INDEPENDENT
// barrier domains per CU: one block's barrier drain / A-publish overlaps the
// other three blocks' MFMA+LDS work (m114 implicit overlap) -- the mechanism
// a monolithic 16-wave block cannot access (R0-R7 evidence: one domain
// locksteps the whole CU at ~47us regardless of schedule).
// Block tile: 128 GEMM rows (64 stm + 64 nstm) x 128 cols, BK=32.
// Waves 2(M)x2(N), each the proven 64x64 tile (4x4 frags of 16x16x32 bf16).
// Swizzle slot = chunk ^ (row&3) on both sides (R2-verified). Schedule =
// R2-verified: [publish A(t)] barrier [stage B-DMA(t+1) + A-load(t+1)]
// [compute t]. XCD swizzle chunk=128: the 4 n-tiles sharing A-rows land on
// one XCD (R5-proven FETCH halving mechanism).
__global__ __launch_bounds__(256, 4) void pn_gemm(
    const float* __restrict__ stm, const float* __restrict__ nstm,
    const unsigned short* __restrict__ W1b, const float* __restrict__ b1,
    const float* __restrict__ W2, float* __restrict__ P)
{
    __shared__ __align__(16) unsigned short As[2][128 * 32];  // 2 x 8 KB
    __shared__ __align__(16) unsigned short Bs[2][128 * 32];  // 2 x 8 KB

    const int tid  = threadIdx.x;
    const int lane = tid & 63;
    const int wave = tid >> 6;    // 0..3
    const int wr   = wave >> 1;   // row band: GEMM rows wr*64 .. +63
    const int wc   = wave & 1;    // col tile: cols wc*64 .. +63 (within BN)
    const int quad = lane >> 4;
    const int l16  = lane & 15;

    // XCD swizzle (bijective: 1024 blocks, 8 XCDs, chunk 128): consecutive
    // sbids = 4 n-tiles of the same bm -> same XCD -> A-rows fetched once
    // per XCD and shared 4-way in its L2.
    const int sbid  = (blockIdx.x & 7) * 128 + (blockIdx.x >> 3);
    const int bm    = sbid >> 2;
    const int n_idx = sbid & 3;
    const int b0    = bm * BMB;       // batch rows owned by this block
    const int n0    = n_idx * BN;     // feature cols owned by this block

    // ---- A staging: thread covers row arow (0..127), chunks ac and ac+2
    const int arow = tid >> 1;
    const int ac   = tid & 1;
    const float* aSrc =
        ((arow < BMB) ? stm  + (size_t)(b0 + arow) * FIN
                      : nstm + (size_t)(b0 + arow - BMB) * FIN);
    const int aOffLo = arow * 32 + ((ac       ^ (arow & 3)) * 8);  // swizzled
    const int aOffHi = arow * 32 + (((ac + 2) ^ (arow & 3)) * 8);

    // ---- B staging: 2 DMA instrs/wave, J = wave*2+i covers rows J*16..+15
    const int brow = lane >> 2;                 // row within 16-group
    const int bch  = (lane & 3) ^ (brow & 3);   // swizzled SOURCE chunk
    const unsigned short* bSrc =
        W1b + (size_t)(n0 + brow) * FIN + bch * 8;

    floatx4 acc[4][4];
    #pragma unroll
    for (int i = 0; i < 4; ++i)
        #pragma unroll
        for (int j = 0; j < 4; ++j)
            acc[i][j] = (floatx4)0.0f;

    // ---- prologue: stage tile 0
    float4 ap0 = *(const float4*)(aSrc + ac * 8);
    float4 ap1 = *(const float4*)(aSrc + ac * 8 + 4);
    float4 ap2 = *(const float4*)(aSrc + (ac + 2) * 8);
    float4 ap3 = *(const float4*)(aSrc + (ac + 2) * 8 + 4);
    #pragma unroll
    for (int i = 0; i < 2; ++i) {
        const int J = wave * 2 + i;
        load_lds_16(bSrc + (size_t)(J * 16) * FIN, &Bs[0][J * 512]);
    }

    for (int t = 0; t < NT; ++t) {
        const int cur = t & 1;
        const int nxt = cur ^ 1;

        // publish A(t) (regs loaded last iter; As[cur] reads drained at barrier t-1)
        {
            uint4 o1, o2;
            o1.x = cvt_pk_bf16(ap0.x, ap0.y); o1.y = cvt_pk_bf16(ap0.z, ap0.w);
            o1.z = cvt_pk_bf16(ap1.x, ap1.y); o1.w = cvt_pk_bf16(ap1.z, ap1.w);
            o2.x = cvt_pk_bf16(ap2.x, ap2.y); o2.y = cvt_pk_bf16(ap2.z, ap2.w);
            o2.z = cvt_pk_bf16(ap3.x, ap3.y); o2.w = cvt_pk_bf16(ap3.z, ap3.w);
            *(uint4*)(&As[cur][aOffLo]) = o1;
            *(uint4*)(&As[cur][aOffHi]) = o2;
        }
        __syncthreads();   // drains B-DMA(t) + A-store(t); protects tile t-1 buffers

        // issue staging for t+1 — lands during tile t's compute
        if (t + 1 < NT) {
            const int kn = (t + 1) * BK;
            #pragma unroll
            for (int i = 0; i < 2; ++i) {
                const int J = wave * 2 + i;
                load_lds_16(bSrc + (size_t)(J * 16) * FIN + kn,
                            &Bs[nxt][J * 512]);
            }
            ap0 = *(const float4*)(aSrc + kn + ac * 8);
            ap1 = *(const float4*)(aSrc + kn + ac * 8 + 4);
            ap2 = *(const float4*)(aSrc + kn + (ac + 2) * 8);
            ap3 = *(const float4*)(aSrc + kn + (ac + 2) * 8 + 4);
        }

        // compute tile t: 8 ds_read_b128 + 16 MFMA
        {
            const int c = quad;   // chunk index 0..3
            short8 af[4], bfr[4];
            #pragma unroll
            for (int mi = 0; mi < 4; ++mi) {
                const int m = wr * 64 + mi * 16 + l16;
                af[mi] = *(const short8*)(&As[cur][m * 32 + ((c ^ (m & 3)) * 8)]);
            }
            #pragma unroll
            for (int ni = 0; ni < 4; ++ni) {
                const int n = wc * 64 + ni * 16 + l16;
                bfr[ni] = *(const short8*)(&Bs[cur][n * 32 + ((c ^ (n & 3)) * 8)]);
            }
            #pragma unroll
            for (int mi = 0; mi < 4; ++mi)
                #pragma unroll
                for (int ni = 0; ni < 4; ++ni)
                    acc[mi][ni] = __builtin_amdgcn_mfma_f32_16x16x32_bf16(
                        af[mi], bfr[ni], acc[mi][ni], 0, 0, 0);
        }
    }

    // ---- fused epilogue. C/D layout: col = lane&15, row = quad*4 + reg.
    // GEMM rows 0-63 (wr=0) = stm -> W2[0..511];
    // rows 64-127 (wr=1) = nstm -> W2[512..1023]. wr is wave-uniform.
    float b1v[4], w2v[4];
    const float* w2base = (wr == 0) ? W2 : W2 + FOUT;
    #pragma unroll
    for (int ni = 0; ni < 4; ++ni) {
        int col = n0 + wc * 64 + ni * 16 + l16;
        b1v[ni] = b1[col];
        w2v[ni] = w2base[col];
    }

    __syncthreads();                 // all MFMA LDS reads done; reuse As
    float* Epi = (float*)As;         // [128 rows][2 wave-cols] partials (1 KB)

    #pragma unroll
    for (int mi = 0; mi < 4; ++mi) {
        #pragma unroll
        for (int r = 0; r < 4; ++r) {
            float s = 0.0f;
            #pragma unroll
            for (int ni = 0; ni < 4; ++ni) {
                float h = acc[mi][ni][r] + b1v[ni];
                h = fminf(fmaxf(h, 0.0f), 1.0f);
                s += h * w2v[ni];
            }
            s += __shfl_xor(s, 1);
            s += __shfl_xor(s, 2);
            s += __shfl_xor(s, 4);
            s += __shfl_xor(s, 8);
            if (l16 == 0) {
                Epi[(wr * 64 + mi * 16 + quad * 4 + r) * 2 + wc] = s;
            }
        }
    }
    __syncthreads();

    // batch row i partial over this block's 128 features =
    // stm-row i partials (rows 0-63) + nstm-row i partials (64-127)
    if (tid < BMB) {
        float x = Epi[tid * 2] + Epi[tid * 2 + 1]
                + Epi[(tid + BMB) * 2] + Epi[(tid + BMB) * 2 + 1];
        P[n_idx * BATCH + b0 + tid] = x;
    }
}

// sum the four N-quarter partials + bias, sigmoid
__global__ __launch_bounds__(256) void finish(
    const float* __restrict__ P, const float* __restrict__ b2,
    float* __restrict__ out)
{
    int i = blockIdx.x * 256 + threadIdx.x;
    float x = b2[0] + P[i] + P[BATCH + i] + P[2 * BATCH + i] + P[3 * BATCH + i];
    out[i] = 1.0f / (1.0f + expf(-x));
}

extern "C" void kernel_launch(void* const* d_in, const int* in_sizes, int n_in,
                              void* d_out, int out_size, void* d_ws, size_t ws_size,
                              hipStream_t stream)
{
    (void)in_sizes; (void)n_in; (void)out_size; (void)ws_size;
    const float* stm  = (const float*)d_in[0];
    const float* nstm = (const float*)d_in[1];
    const float* W1   = (const float*)d_in[2];
    const float* b1   = (const float*)d_in[3];
    const float* W2   = (const float*)d_in[4];
    const float* b2   = (const float*)d_in[5];
    float* out = (float*)d_out;
    unsigned short* W1b = (unsigned short*)d_ws;           // bf16 W1 (768 KB)
    float* P = (float*)((char*)d_ws + FOUT * FIN * 2);     // partials (256 KB)

    cvt_w1<<<dim3((FOUT * FIN) / (256 * 8)), dim3(256), 0, stream>>>(W1, W1b);
    pn_gemm<<<dim3((BATCH / BMB) * 4), dim3(256), 0, stream>>>(
        stm, nstm, W1b, b1, W2, P);
    finish<<<dim3(BATCH / 256), dim3(256), 0, stream>>>(P, b2, out);
}

// Round 9
// 160.560 us; speedup vs baseline: 1.0470x; 1.0470x over previous
//
#include <hip/hip_runtime.h>
#include <hip/hip_bf16.h>

#define BATCH 16384
#define FIN   768
#define FOUT  512

#define BK 32
#define NT (FIN / BK)   // 24 K-iterations
#define BM 128          // batch rows per block -> 256 GEMM rows (stm+nstm)
#define BN 256          // feature cols per block (N-split x2)

typedef __attribute__((ext_vector_type(8))) short short8;
typedef __attribute__((ext_vector_type(4))) float floatx4;

// packed fp32x2 -> bf16x2, round-to-nearest-even (gfx940+ VOP3)
__device__ __forceinline__ unsigned int cvt_pk_bf16(float a, float b) {
    unsigned int r;
    asm("v_cvt_pk_bf16_f32 %0, %1, %2" : "=v"(r) : "v"(a), "v"(b));
    return r;
}

// async 16B global -> LDS DMA; HW scatters lane i to ldsbase + i*16
__device__ __forceinline__ void load_lds_16(const void* g, void* l) {
    __builtin_amdgcn_global_load_lds(
        (const __attribute__((address_space(1))) unsigned int*)g,
        (__attribute__((address_space(3))) unsigned int*)l,
        16, 0, 0);
}

// Counted-vmcnt barrier (T4): at BAR(t) each wave has 6 outstanding DMAs
// (groups t and t+1, 3 each, in-order); vmcnt(3) drains exactly group t
// (tile t's data) while group t+1 rides across. lgkmcnt(0) retires this
// wave's ds_reads so DMA(t+2) can't overwrite a buffer still being read.
#define BAR_VM3() do {                                               \
    __builtin_amdgcn_sched_barrier(0);                               \
    asm volatile("s_waitcnt vmcnt(3) lgkmcnt(0)" ::: "memory");      \
    __builtin_amdgcn_s_barrier();                                    \
    __builtin_amdgcn_sched_barrier(0);                               \
} while (0)
#define BAR_VM0() do {                                               \
    __builtin_amdgcn_sched_barrier(0);                               \
    asm volatile("s_waitcnt vmcnt(0) lgkmcnt(0)" ::: "memory");      \
    __builtin_amdgcn_s_barrier();                                    \
    __builtin_amdgcn_sched_barrier(0);                               \
} while (0)

// one-shot W1 fp32 -> bf16 (393216 elems, 8 per thread, 192 blocks)
__global__ __launch_bounds__(256) void cvt_w1(
    const float* __restrict__ W1, unsigned short* __restrict__ W1b)
{
    int base = (blockIdx.x * 256 + threadIdx.x) * 8;
    float4 a = *(const float4*)(W1 + base);
    float4 b = *(const float4*)(W1 + base + 4);
    uint4 o;
    o.x = cvt_pk_bf16(a.x, a.y); o.y = cvt_pk_bf16(a.z, a.w);
    o.z = cvt_pk_bf16(b.x, b.y); o.w = cvt_pk_bf16(b.z, b.w);
    *(uint4*)(W1b + base) = o;
}

// 256 blocks x 1024 threads, 1 block/CU (144 KB LDS). R5 geometry (16 waves
// x 64x64 tiles, BM=128 -> 256 GEMM rows, BN=256, XCD-pair swizzle) with the
// A REGISTER CHAIN ELIMINATED: A is DMA'd to LDS as raw fp32 (triple-
// buffered, like B) and converted to bf16 at frag-read time (2 float4 LDS
// reads + 4 cvt_pk per frag). The K-loop is m201-pure -- every phase is only
// {counted barrier -> issue 3 DMAs -> ds_read/cvt -> MFMA}; no register-
// dependent vmem wait exists anywhere in the loop (9 rounds of evidence say
// that publish chain was the structural stall every variant shared).
// A-swizzle: pre-swizzled per-lane SOURCE chunk (lane&7)^(lane>>3); read at
// 16B-chunk (2*quad+h)^(m&7) -> 2-way residual conflicts (free, m136).
// B path verbatim from R2/R5 (verified): slot = chunk ^ (row&3).
__global__ __launch_bounds__(1024, 4) void pn_gemm(
    const float* __restrict__ stm, const float* __restrict__ nstm,
    const unsigned short* __restrict__ W1b, const float* __restrict__ b1,
    const float* __restrict__ W2, float* __restrict__ P)
{
    __shared__ __align__(16) float          Asf[3][256 * 32];  // 3 x 32 KB fp32
    __shared__ __align__(16) unsigned short Bs[3][256 * 32];   // 3 x 16 KB bf16

    const int tid  = threadIdx.x;
    const int lane = tid & 63;
    const int wave = tid >> 6;    // 0..15
    const int wr   = wave >> 2;   // row tile: GEMM rows wr*64 .. +63
    const int wc   = wave & 3;    // col tile: cols wc*64 .. +63 (within BN)
    const int quad = lane >> 4;
    const int l16  = lane & 15;

    // XCD-pair swizzle (bijective: 256 blocks, 8 XCDs, chunk 32): the
    // (bm, n_idx=0/1) pair gets consecutive sbids -> same XCD -> shared L2.
    const int sbid  = (blockIdx.x & 7) * 32 + (blockIdx.x >> 3);
    const int bm    = sbid >> 1;
    const int n_idx = sbid & 1;
    const int b0    = bm * BM;        // batch rows owned by this block
    const int n0    = n_idx * BN;     // feature cols owned by this block

    // ---- A staging: 2 DMA instrs/wave, instr J = wave*2+i covers rows
    // J*8..+7 (8 rows x 32 fp32 = 1 KB). Lane l -> row J*8+(l>>3), 16B-slot
    // l&7; source chunk pre-swizzled: (l&7)^(l>>3)  [row&7 == l>>3 here].
    const int aRowIn = (lane >> 3);               // row within 8-group
    const int aChunk = (lane & 7) ^ aRowIn;       // swizzled SOURCE 16B-chunk
    const int arow0  = (wave * 2 + 0) * 8 + aRowIn;
    const int arow1  = (wave * 2 + 1) * 8 + aRowIn;
    const float* aSrc0 =
        ((arow0 < BM) ? stm  + (size_t)(b0 + arow0) * FIN
                      : nstm + (size_t)(b0 + arow0 - BM) * FIN) + aChunk * 4;
    const float* aSrc1 =
        ((arow1 < BM) ? stm  + (size_t)(b0 + arow1) * FIN
                      : nstm + (size_t)(b0 + arow1 - BM) * FIN) + aChunk * 4;
    const int aDst0 = (wave * 2 + 0) * 256;   // float index into Asf[buf]
    const int aDst1 = (wave * 2 + 1) * 256;

    // ---- B staging: 1 DMA instr/wave, wave covers rows wave*16..+15.
    // Lane l -> row l>>2, 16B-slot l&3; source chunk (l&3)^(row&3). (R2)
    const int brow = lane >> 2;
    const int bch  = (lane & 3) ^ (brow & 3);
    const unsigned short* bSrc =
        W1b + (size_t)(n0 + wave * 16 + brow) * FIN + bch * 8;

    floatx4 acc[4][4];
    #pragma unroll
    for (int i = 0; i < 4; ++i)
        #pragma unroll
        for (int j = 0; j < 4; ++j)
            acc[i][j] = (floatx4)0.0f;

    // ---- prologue: DMA groups for tile 0 (buf 0) and tile 1 (buf 1)
    load_lds_16(aSrc0,      &Asf[0][aDst0]);
    load_lds_16(aSrc1,      &Asf[0][aDst1]);
    load_lds_16(bSrc,       &Bs[0][wave * 512]);
    load_lds_16(aSrc0 + BK, &Asf[1][aDst0]);
    load_lds_16(aSrc1 + BK, &Asf[1][aDst1]);
    load_lds_16(bSrc + BK,  &Bs[1][wave * 512]);

    int bc = 0;   // buffer holding tile t
    for (int t = 0; t < NT; ++t) {
        // tile t's group is the oldest 3 outstanding -> drain it; keep t+1's
        if (t + 1 < NT) { BAR_VM3(); } else { BAR_VM0(); }

        // issue group t+2 into buffer (t+2)%3 (read-drained at this barrier)
        if (t + 2 < NT) {
            int bp = bc + 2; if (bp >= 3) bp -= 3;
            const int kn = (t + 2) * BK;
            load_lds_16(aSrc0 + kn, &Asf[bp][aDst0]);
            load_lds_16(aSrc1 + kn, &Asf[bp][aDst1]);
            load_lds_16(bSrc + kn,  &Bs[bp][wave * 512]);
        }

        // compute tile t: A frags read as fp32 + cvt_pk, B frags as bf16
        short8 af[4], bfr[4];
        #pragma unroll
        for (int mi = 0; mi < 4; ++mi) {
            const int m = wr * 64 + mi * 16 + l16;
            const float* ar = &Asf[bc][m * 32];
            float4 lo = *(const float4*)(ar + (((2 * quad    ) ^ (l16 & 7)) << 2));
            float4 hi = *(const float4*)(ar + (((2 * quad + 1) ^ (l16 & 7)) << 2));
            uint4 o;
            o.x = cvt_pk_bf16(lo.x, lo.y); o.y = cvt_pk_bf16(lo.z, lo.w);
            o.z = cvt_pk_bf16(hi.x, hi.y); o.w = cvt_pk_bf16(hi.z, hi.w);
            af[mi] = *(short8*)&o;
        }
        #pragma unroll
        for (int ni = 0; ni < 4; ++ni) {
            const int n = wc * 64 + ni * 16 + l16;
            bfr[ni] = *(const short8*)(&Bs[bc][n * 32 + ((quad ^ (n & 3)) * 8)]);
        }
        #pragma unroll
        for (int mi = 0; mi < 4; ++mi)
            #pragma unroll
            for (int ni = 0; ni < 4; ++ni)
                acc[mi][ni] = __builtin_amdgcn_mfma_f32_16x16x32_bf16(
                    af[mi], bfr[ni], acc[mi][ni], 0, 0, 0);

        bc = (bc == 2) ? 0 : bc + 1;
    }

    // ---- fused epilogue. C/D layout: col = lane&15, row = quad*4 + reg.
    // GEMM rows 0-127 (wr 0,1) = stm -> W2[0..511];
    // rows 128-255 (wr 2,3) = nstm -> W2[512..1023]. wr is wave-uniform.
    float b1v[4], w2v[4];
    const float* w2base = (wr < 2) ? W2 : W2 + FOUT;
    #pragma unroll
    for (int ni = 0; ni < 4; ++ni) {
        int col = n0 + wc * 64 + ni * 16 + l16;
        b1v[ni] = b1[col];
        w2v[ni] = w2base[col];
    }

    __syncthreads();                 // all LDS reads done; reuse Asf
    float* Epi = (float*)Asf;        // [256 rows][4 wave-cols] partials (4 KB)

    #pragma unroll
    for (int mi = 0; mi < 4; ++mi) {
        #pragma unroll
        for (int r = 0; r < 4; ++r) {
            float s = 0.0f;
            #pragma unroll
            for (int ni = 0; ni < 4; ++ni) {
                float h = acc[mi][ni][r] + b1v[ni];
                h = fminf(fmaxf(h, 0.0f), 1.0f);
                s += h * w2v[ni];
            }
            s += __shfl_xor(s, 1);
            s += __shfl_xor(s, 2);
            s += __shfl_xor(s, 4);
            s += __shfl_xor(s, 8);
            if (l16 == 0) {
                Epi[(wr * 64 + mi * 16 + quad * 4 + r) * 4 + wc] = s;
            }
        }
    }
    __syncthreads();

    // batch row i partial over this block's 256 features =
    // stm-row i partials (rows 0-127) + nstm-row i partials (128-255)
    if (tid < BM) {
        float x = 0.0f;
        #pragma unroll
        for (int j = 0; j < 4; ++j)
            x += Epi[tid * 4 + j] + Epi[(tid + BM) * 4 + j];
        P[n_idx * BATCH + b0 + tid] = x;
    }
}

// sum the two N-half partials + bias, sigmoid
__global__ __launch_bounds__(256) void finish(
    const float* __restrict__ P, const float* __restrict__ b2,
    float* __restrict__ out)
{
    int i = blockIdx.x * 256 + threadIdx.x;
    float x = b2[0] + P[i] + P[BATCH + i];
    out[i] = 1.0f / (1.0f + expf(-x));
}

extern "C" void kernel_launch(void* const* d_in, const int* in_sizes, int n_in,
                              void* d_out, int out_size, void* d_ws, size_t ws_size,
                              hipStream_t stream)
{
    (void)in_sizes; (void)n_in; (void)out_size; (void)ws_size;
    const float* stm  = (const float*)d_in[0];
    const float* nstm = (const float*)d_in[1];
    const float* W1   = (const float*)d_in[2];
    const float* b1   = (const float*)d_in[3];
    const float* W2   = (const float*)d_in[4];
    const float* b2   = (const float*)d_in[5];
    float* out = (float*)d_out;
    unsigned short* W1b = (unsigned short*)d_ws;           // bf16 W1 (768 KB)
    float* P = (float*)((char*)d_ws + FOUT * FIN * 2);     // partials (128 KB)

    cvt_w1<<<dim3((FOUT * FIN) / (256 * 8)), dim3(256), 0, stream>>>(W1, W1b);
    pn_gemm<<<dim3((BATCH / BM) * 2), dim3(1024), 0, stream>>>(
        stm, nstm, W1b, b1, W2, P);
    finish<<<dim3(BATCH / 256), dim3(256), 0, stream>>>(P, b2, out);
}